// Round 11
// baseline (334.908 us; speedup 1.0000x reference)
//
#include <hip/hip_runtime.h>

#define NN   50000
#define NE   800000
#define IND  128
#define HIDD 96
#define OUTD 128
#define CATD (4 * HIDD)   // 384
#define CAP  64
#define NBIN 49           // dst >> 10 -> 49 bins of 1024 nodes
#define BCH  4096         // edges per binfill block

typedef __attribute__((ext_vector_type(8))) short short8v;
typedef __attribute__((ext_vector_type(4))) float f32x4;

__device__ __forceinline__ ushort f2bf(float f) {
    unsigned u = __float_as_uint(f);
    u = (u + 0x7FFFu + ((u >> 16) & 1u)) >> 16;
    return (ushort)u;
}
__device__ __forceinline__ float bf2f(ushort h) {
    return __uint_as_float(((unsigned)h) << 16);
}
__device__ __forceinline__ float blo(unsigned u) { return __uint_as_float(u << 16); }
__device__ __forceinline__ float bhi(unsigned u) { return __uint_as_float(u & 0xffff0000u); }

// ---------------------------------------------------------------------------
// Weight regions (in whi/wlo): row-major {W_in, W_layers, W_out} then
// frag-ordered W_layers + W_out (see r7 comment for the frag mapping).
// ---------------------------------------------------------------------------
#define NW_IN  (HIDD * IND)
#define NW_L   (3 * HIDD * HIDD)
#define NW_OUT (OUTD * CATD)
#define NW_ROW (NW_IN + NW_L + NW_OUT)
#define NW_ALL (NW_ROW + NW_L + NW_OUT)

__global__ __launch_bounds__(256)
void wsplit_k(const float* __restrict__ Wi, const float* __restrict__ Wl,
              const float* __restrict__ Wo,
              ushort* __restrict__ whi, ushort* __restrict__ wlo)
{
    int i = blockIdx.x * 256 + threadIdx.x;
    if (i >= NW_ALL) return;
    float v;
    if (i < NW_ROW) {
        if (i < NW_IN)              v = Wi[i];
        else if (i < NW_IN + NW_L)  v = Wl[i - NW_IN];
        else                        v = Wo[i - NW_IN - NW_L];
    } else if (i < NW_ROW + NW_L) {
        int fi = i - NW_ROW;
        int l  = fi / 9216;
        int r  = fi - l * 9216;
        int c  = r / 1536;
        int ks = (r % 1536) / 512;
        int ln = (r % 512) / 8;
        int t  = r & 7;
        int j  = c * 16 + (ln & 15);
        int k  = ks * 32 + 8 * (ln >> 4) + t;
        v = Wl[(l * HIDD + j) * HIDD + k];
    } else {
        int fi = i - NW_ROW - NW_L;
        int c  = fi / 6144;
        int r  = fi - c * 6144;
        int ks = r / 512;
        int ln = (r % 512) / 8;
        int t  = r & 7;
        int j  = c * 16 + (ln & 15);
        int k  = ks * 32 + 8 * (ln >> 4) + t;
        v = Wo[j * CATD + k];
    }
    ushort h = f2bf(v);
    whi[i] = h;
    wlo[i] = f2bf(v - bf2f(h));
}

// ---------------------------------------------------------------------------
// MFMA GEMM (row-major W staged in LDS); optional fused bf16 copy of C
// (valid only when NCOLS==HIDD; pass nullptr otherwise).
// ---------------------------------------------------------------------------
template<int K, int NCOLS, int ROWS, bool ACCUM>
__global__ __launch_bounds__(256)
void mgemm_k(const float* __restrict__ A,
             const ushort* __restrict__ Whi, const ushort* __restrict__ Wlo,
             int wstride, const float* __restrict__ bias,
             float* __restrict__ C, int cstride, int nrows,
             ushort* __restrict__ bfC)
{
    constexpr int ST  = K + 8;
    constexpr int KS  = K / 32;
    constexpr int TRP = (ROWS / 16) / 2;
    constexpr int TCP = (NCOLS / 16) / 2;
    constexpr int CPR = K / 8;

    __shared__ __align__(16) ushort sWh[NCOLS * ST];
    __shared__ __align__(16) ushort sWl[NCOLS * ST];

    const int tid  = threadIdx.x;
    const int w    = tid >> 6;
    const int l    = tid & 63;
    const int lr   = l & 15;
    const int lg   = l >> 4;
    const int row0 = blockIdx.x * ROWS;

    for (int idx = tid; idx < NCOLS * CPR; idx += 256) {
        int j = idx / CPR, c = idx - j * CPR;
        *(uint4*)&sWh[j * ST + c * 8] = *(const uint4*)&Whi[(long)j * wstride + c * 8];
        *(uint4*)&sWl[j * ST + c * 8] = *(const uint4*)&Wlo[(long)j * wstride + c * 8];
    }

    short8v Ah[TRP][KS], Al[TRP][KS];
#pragma unroll
    for (int i = 0; i < TRP; i++) {
        const int row = row0 + ((w >> 1) + 2 * i) * 16 + lr;
#pragma unroll
        for (int ks = 0; ks < KS; ks++) {
            float4 r0 = make_float4(0.f, 0.f, 0.f, 0.f);
            float4 r1 = make_float4(0.f, 0.f, 0.f, 0.f);
            if (row < nrows) {
                const float* p = &A[(long)row * K + ks * 32 + 8 * lg];
                r0 = *(const float4*)p;
                r1 = *(const float4*)(p + 4);
            }
            const float f[8] = {r0.x, r0.y, r0.z, r0.w, r1.x, r1.y, r1.z, r1.w};
            short8v hi, lo;
#pragma unroll
            for (int t = 0; t < 8; t++) {
                ushort h = f2bf(f[t]);
                hi[t] = (short)h;
                lo[t] = (short)f2bf(f[t] - bf2f(h));
            }
            Ah[i][ks] = hi;
            Al[i][ks] = lo;
        }
    }
    __syncthreads();

#pragma unroll
    for (int j = 0; j < TCP; j++) {
        const int colb = ((w & 1) + 2 * j) * 16;
        short8v Bh[KS], Bl[KS];
#pragma unroll
        for (int ks = 0; ks < KS; ks++) {
            Bh[ks] = *(const short8v*)&sWh[(colb + lr) * ST + ks * 32 + 8 * lg];
            Bl[ks] = *(const short8v*)&sWl[(colb + lr) * ST + ks * 32 + 8 * lg];
        }
        const float bv = bias ? bias[colb + lr] : 0.f;
#pragma unroll
        for (int i = 0; i < TRP; i++) {
            f32x4 acc = {bv, bv, bv, bv};
#pragma unroll
            for (int ks = 0; ks < KS; ks++) {
                acc = __builtin_amdgcn_mfma_f32_16x16x32_bf16(Ah[i][ks], Bh[ks], acc, 0, 0, 0);
                acc = __builtin_amdgcn_mfma_f32_16x16x32_bf16(Ah[i][ks], Bl[ks], acc, 0, 0, 0);
                acc = __builtin_amdgcn_mfma_f32_16x16x32_bf16(Al[i][ks], Bh[ks], acc, 0, 0, 0);
            }
#pragma unroll
            for (int p = 0; p < 4; p++) {
                const int row = row0 + ((w >> 1) + 2 * i) * 16 + 4 * lg + p;
                if (row < nrows) {
                    float* cp = &C[(long)row * cstride + colb + lr];
                    if (ACCUM) *cp += acc[p];
                    else       *cp  = acc[p];
                    if (bfC)
                        bfC[(long)row * HIDD + colb + lr] = f2bf(acc[p]);
                }
            }
        }
    }
}

// ---------------------------------------------------------------------------
// Two-phase binned bucket build (kills the 7x cross-XCD write amplification
// measured on the one-pass scatter: WRITE_SIZE 44MB for a 6.4MB bucket).
// ---------------------------------------------------------------------------
__global__ __launch_bounds__(256)
void hist_k(const int* __restrict__ ei, int* __restrict__ binCount)
{
    __shared__ int h[NBIN];
    for (int b = threadIdx.x; b < NBIN; b += 256) h[b] = 0;
    __syncthreads();
    int e0 = (blockIdx.x * 256 + threadIdx.x) * 4;
    if (e0 + 4 <= NE) {
        const int4 d4 = *(const int4*)&ei[NE + e0];
        atomicAdd(&h[d4.x >> 10], 1);
        atomicAdd(&h[d4.y >> 10], 1);
        atomicAdd(&h[d4.z >> 10], 1);
        atomicAdd(&h[d4.w >> 10], 1);
    }
    __syncthreads();
    for (int b = threadIdx.x; b < NBIN; b += 256)
        if (h[b]) atomicAdd(&binCount[b], h[b]);
}

__global__ __launch_bounds__(64)
void binscan_k(const int* __restrict__ binCount, int* __restrict__ binStart,
               int* __restrict__ binCursor)
{
    __shared__ int v[64];
    const int t = threadIdx.x;
    int x = (t < NBIN) ? binCount[t] : 0;
    v[t] = x;
    __syncthreads();
    for (int off = 1; off < 64; off <<= 1) {
        int tmp = (t >= off) ? v[t - off] : 0;
        __syncthreads();
        v[t] += tmp;
        __syncthreads();
    }
    if (t < NBIN) { int ex = v[t] - x; binStart[t] = ex; binCursor[t] = ex; }
    if (t == NBIN - 1) binStart[NBIN] = v[t];
}

// Bin edges in LDS, reserve contiguous global ranges, flush as bursts.
__global__ __launch_bounds__(256)
void binfill_k(const int* __restrict__ ei, int* __restrict__ binCursor,
               unsigned* __restrict__ binned)
{
    __shared__ unsigned sbuf[BCH];
    __shared__ int lcnt[NBIN], lstart[NBIN], lcur[NBIN], gbase[NBIN];
    const int tid  = threadIdx.x;
    const int base = blockIdx.x * BCH;

    for (int b = tid; b < NBIN; b += 256) { lcnt[b] = 0; lcur[b] = 0; }
    __syncthreads();

    unsigned ent[16];
#pragma unroll
    for (int r = 0; r < 16; r++) {
        const int e = base + r * 256 + tid;
        if (e < NE) {
            const int s = ei[e];
            const int d = ei[NE + e];
            ent[r] = ((unsigned)d << 16) | (unsigned)s;
            atomicAdd(&lcnt[d >> 10], 1);
        } else {
            ent[r] = 0xffffffffu;
        }
    }
    __syncthreads();
    if (tid == 0) {
        int run = 0;
        for (int b = 0; b < NBIN; b++) { lstart[b] = run; run += lcnt[b]; }
    }
    __syncthreads();
    if (tid < NBIN) gbase[tid] = atomicAdd(&binCursor[tid], lcnt[tid]);
    __syncthreads();
#pragma unroll
    for (int r = 0; r < 16; r++) {
        if (ent[r] != 0xffffffffu) {
            const int bin = ent[r] >> 26;              // == dst >> 10
            const int pos = atomicAdd(&lcur[bin], 1);
            sbuf[lstart[bin] + pos] = ent[r];
        }
    }
    __syncthreads();
    const int total = lstart[NBIN - 1] + lcnt[NBIN - 1];
    for (int i = tid; i < total; i += 256) {
        const unsigned e = sbuf[i];
        const int bin = e >> 26;
        binned[gbase[bin] + (i - lstart[bin])] = e;
    }
}

// One block per bin: bucket slice (128KB) is single-XCD L2 resident.
__global__ __launch_bounds__(1024)
void bfill_k(const unsigned* __restrict__ binned, const int* __restrict__ binStart,
             int* __restrict__ cursor, ushort* __restrict__ bucket)
{
    const int b   = blockIdx.x;
    const int beg = binStart[b], end = binStart[b + 1];
    for (int i = beg + threadIdx.x; i < end; i += 1024) {
        const unsigned e = binned[i];
        const int d = e >> 16;
        const int s = e & 0xffffu;
        const int pos = atomicAdd(&cursor[d], 1);
        if (pos < CAP) bucket[(long)d * CAP + pos] = (ushort)s;
    }
}

// ---------------------------------------------------------------------------
// Fused layer: self fp32 + neighbors bf16; ushort bucket (pair-packed loads).
// 256 thr = 32 nodes x 8 strips.
// ---------------------------------------------------------------------------
#define FROWS 32
#define FAST  100

__global__ __launch_bounds__(256)
void flayer_k(const float* __restrict__ hf_in, int istride,
              const ushort* __restrict__ hb_in,
              const int* __restrict__ cursor, const ushort* __restrict__ bucket,
              const ushort* __restrict__ fWhi, const ushort* __restrict__ fWlo,
              const float* __restrict__ bias,
              float* __restrict__ hf_out, int ostride,
              ushort* __restrict__ hb_out)
{
    __shared__ __align__(16) float sA[FROWS * FAST];

    const int tid = threadIdx.x;
    const int n0  = blockIdx.x * FROWS;

    {
        const int i  = tid >> 3;
        const int st = tid & 7;
        const int n  = n0 + i;
        float4 s0 = make_float4(0.f, 0.f, 0.f, 0.f);
        float4 s1 = s0, s2 = s0;
        if (n < NN) {
            const float* hp = &hf_in[(long)n * istride + st * 12];
            s0 = ((const float4*)hp)[0];
            s1 = *(const float4*)(hp + 4);
            s2 = *(const float4*)(hp + 8);
            int cnt = cursor[n];
            if (cnt > CAP) cnt = CAP;
            const ushort* bp = &bucket[(long)n * CAP];
            const ushort* hbb = hb_in + st * 12;
#define ACCB(q)                                                              \
            { const uint2 a = *(const uint2*)(q);                            \
              const uint2 b = *(const uint2*)((q) + 4);                      \
              const uint2 c = *(const uint2*)((q) + 8);                      \
              s0.x += blo(a.x); s0.y += bhi(a.x); s0.z += blo(a.y); s0.w += bhi(a.y); \
              s1.x += blo(b.x); s1.y += bhi(b.x); s1.z += blo(b.y); s1.w += bhi(b.y); \
              s2.x += blo(c.x); s2.y += bhi(c.x); s2.z += blo(c.y); s2.w += bhi(c.y); }
            int e = 0;
            for (; e + 1 < cnt; e += 2) {
                const unsigned id2 = *(const unsigned*)&bp[e];
                const ushort* q0 = &hbb[(long)(id2 & 0xffffu) * HIDD];
                const ushort* q1 = &hbb[(long)(id2 >> 16) * HIDD];
                ACCB(q0); ACCB(q1);
            }
            if (e < cnt) {
                const ushort* q = &hbb[(long)bp[e] * HIDD];
                ACCB(q);
            }
#undef ACCB
        }
        float* ap = &sA[i * FAST + st * 12];
        ((float4*)ap)[0] = s0;
        ((float4*)ap)[1] = s1;
        ((float4*)ap)[2] = s2;
    }
    __syncthreads();

    const int w  = tid >> 6;
    const int l  = tid & 63;
    const int lr = l & 15;
    const int lg = l >> 4;
    const int tr = w >> 1;

    short8v Ah[3], Al[3];
#pragma unroll
    for (int ks = 0; ks < 3; ks++) {
        const float* ap = &sA[(tr * 16 + lr) * FAST + ks * 32 + 8 * lg];
        const float4 r0 = ((const float4*)ap)[0];
        const float4 r1 = ((const float4*)ap)[1];
        const float f[8] = {r0.x, r0.y, r0.z, r0.w, r1.x, r1.y, r1.z, r1.w};
        short8v hi, lo;
#pragma unroll
        for (int t = 0; t < 8; t++) {
            ushort h = f2bf(f[t]);
            hi[t] = (short)h;
            lo[t] = (short)f2bf(f[t] - bf2f(h));
        }
        Ah[ks] = hi;
        Al[ks] = lo;
    }

#pragma unroll
    for (int j = 0; j < 3; j++) {
        const int c    = (w & 1) + 2 * j;
        const int colb = c * 16;
        short8v Bh[3], Bl[3];
#pragma unroll
        for (int ks = 0; ks < 3; ks++) {
            Bh[ks] = *(const short8v*)&fWhi[((c * 3 + ks) * 64 + l) * 8];
            Bl[ks] = *(const short8v*)&fWlo[((c * 3 + ks) * 64 + l) * 8];
        }
        const float bv = bias[colb + lr];
        f32x4 acc = {bv, bv, bv, bv};
#pragma unroll
        for (int ks = 0; ks < 3; ks++) {
            acc = __builtin_amdgcn_mfma_f32_16x16x32_bf16(Ah[ks], Bh[ks], acc, 0, 0, 0);
            acc = __builtin_amdgcn_mfma_f32_16x16x32_bf16(Ah[ks], Bl[ks], acc, 0, 0, 0);
            acc = __builtin_amdgcn_mfma_f32_16x16x32_bf16(Al[ks], Bh[ks], acc, 0, 0, 0);
        }
#pragma unroll
        for (int p = 0; p < 4; p++) {
            const int row = n0 + tr * 16 + 4 * lg + p;
            if (row < NN) {
                hf_out[(long)row * ostride + colb + lr] = acc[p];
                if (hb_out)
                    hb_out[(long)row * HIDD + colb + lr] = f2bf(acc[p]);
            }
        }
    }
}

// ---------------------------------------------------------------------------
// Final GEMM: out[NN][128] = cat[NN][384] @ W_out^T + b_out (32 rows/block)
// ---------------------------------------------------------------------------
__global__ __launch_bounds__(256)
void fgemm_k(const float* __restrict__ cat, const ushort* __restrict__ fOhi,
             const ushort* __restrict__ fOlo, const float* __restrict__ bias,
             float* __restrict__ out)
{
    const int tid  = threadIdx.x;
    const int w    = tid >> 6;
    const int l    = tid & 63;
    const int lr   = l & 15;
    const int lg   = l >> 4;
    const int row0 = blockIdx.x * 32;
    const int rt   = w >> 1;
    const int ch   = w & 1;
    const int arow = row0 + rt * 16 + lr;

    f32x4 acc[4];
#pragma unroll
    for (int j = 0; j < 4; j++) {
        const float bv = bias[(ch + 2 * j) * 16 + lr];
        acc[j] = (f32x4){bv, bv, bv, bv};
    }

#pragma unroll 4
    for (int ks = 0; ks < 12; ks++) {
        float4 r0 = make_float4(0.f, 0.f, 0.f, 0.f);
        float4 r1 = make_float4(0.f, 0.f, 0.f, 0.f);
        if (arow < NN) {
            const float* p = &cat[(long)arow * CATD + ks * 32 + 8 * lg];
            r0 = *(const float4*)p;
            r1 = *(const float4*)(p + 4);
        }
        const float f[8] = {r0.x, r0.y, r0.z, r0.w, r1.x, r1.y, r1.z, r1.w};
        short8v Ah, Al;
#pragma unroll
        for (int t = 0; t < 8; t++) {
            ushort h = f2bf(f[t]);
            Ah[t] = (short)h;
            Al[t] = (short)f2bf(f[t] - bf2f(h));
        }
#pragma unroll
        for (int j = 0; j < 4; j++) {
            const int c = ch + 2 * j;
            const short8v Bh = *(const short8v*)&fOhi[((c * 12 + ks) * 64 + l) * 8];
            const short8v Bl = *(const short8v*)&fOlo[((c * 12 + ks) * 64 + l) * 8];
            acc[j] = __builtin_amdgcn_mfma_f32_16x16x32_bf16(Ah, Bh, acc[j], 0, 0, 0);
            acc[j] = __builtin_amdgcn_mfma_f32_16x16x32_bf16(Ah, Bl, acc[j], 0, 0, 0);
            acc[j] = __builtin_amdgcn_mfma_f32_16x16x32_bf16(Al, Bh, acc[j], 0, 0, 0);
        }
    }

#pragma unroll
    for (int p = 0; p < 4; p++) {
        const int row = row0 + rt * 16 + 4 * lg + p;
        if (row < NN) {
#pragma unroll
            for (int j = 0; j < 4; j++)
                out[(long)row * OUTD + (ch + 2 * j) * 16 + lr] = acc[j][p];
        }
    }
}

// ---------------------------------------------------------------------------
extern "C" void kernel_launch(void* const* d_in, const int* in_sizes, int n_in,
                              void* d_out, int out_size, void* d_ws, size_t ws_size,
                              hipStream_t stream)
{
    const float* x  = (const float*)d_in[0];
    const int*   ei = (const int*)  d_in[1];
    const float* Wi = (const float*)d_in[2];
    const float* bi = (const float*)d_in[3];
    const float* Wl = (const float*)d_in[4];
    const float* bl = (const float*)d_in[5];
    const float* Wo = (const float*)d_in[6];
    const float* bo = (const float*)d_in[7];
    float* out = (float*)d_out;

    char* p = (char*)d_ws;
    int* cursor    = (int*)p;              p += ((size_t)(NN + 2 * NBIN + NBIN + 1) * 4 + 255) & ~255ull;
    int* binCount  = cursor + NN;
    int* binCursor = binCount + NBIN;
    int* binStart  = binCursor + NBIN;     // [NBIN+1]
    ushort* bucket = (ushort*)p;           p += ((size_t)NN * CAP * 2 + 255) & ~255ull;
    unsigned* binned = (unsigned*)p;       p += ((size_t)NE * 4 + 255) & ~255ull;
    ushort* whi = (ushort*)p;              p += ((size_t)NW_ALL * 2 + 255) & ~255ull;
    ushort* wlo = (ushort*)p;              p += ((size_t)NW_ALL * 2 + 255) & ~255ull;
    ushort* hbfA = (ushort*)p;             p += ((size_t)NN * HIDD * 2 + 255) & ~255ull;
    ushort* hbfB = (ushort*)p;             p += ((size_t)NN * HIDD * 2 + 255) & ~255ull;
    float* big  = (float*)p;
    const size_t used = (size_t)(p - (char*)d_ws);
    const bool catpath = (ws_size >= used + (size_t)NN * CATD * 4);

    const ushort* whi_in = whi;
    const ushort* wlo_in = wlo;
    const ushort* whi_o  = whi + NW_IN + NW_L;
    const ushort* wlo_o  = wlo + NW_IN + NW_L;
    const ushort* fLhi   = whi + NW_ROW;
    const ushort* fLlo   = wlo + NW_ROW;
    const ushort* fOhi   = whi + NW_ROW + NW_L;
    const ushort* fOlo   = wlo + NW_ROW + NW_L;

    hipLaunchKernelGGL(wsplit_k, dim3((NW_ALL + 255) / 256), dim3(256), 0, stream,
                       Wi, Wl, Wo, whi, wlo);
    // zero cursor + binCount + binCursor in one memset (contiguous)
    hipMemsetAsync(cursor, 0, (size_t)(NN + 2 * NBIN) * sizeof(int), stream);
    hipLaunchKernelGGL(hist_k, dim3((NE / 4 + 255) / 256), dim3(256), 0, stream,
                       ei, binCount);
    hipLaunchKernelGGL(binscan_k, dim3(1), dim3(64), 0, stream,
                       binCount, binStart, binCursor);
    hipLaunchKernelGGL(binfill_k, dim3((NE + BCH - 1) / BCH), dim3(256), 0, stream,
                       ei, binCursor, binned);
    hipLaunchKernelGGL(bfill_k, dim3(NBIN), dim3(1024), 0, stream,
                       binned, binStart, cursor, bucket);

    if (catpath) {
        float* cat = big;                          // [NN][384]
        hipLaunchKernelGGL((mgemm_k<IND, HIDD, 32, false>),
                           dim3((NN + 31) / 32), dim3(256), 0, stream,
                           x, whi_in, wlo_in, IND, bi, cat, CATD, NN, hbfA);
        hipLaunchKernelGGL(flayer_k, dim3((NN + FROWS - 1) / FROWS), dim3(256), 0, stream,
                           cat, CATD, hbfA, cursor, bucket,
                           fLhi, fLlo, bl, cat + HIDD, CATD, hbfB);
        hipLaunchKernelGGL(flayer_k, dim3((NN + FROWS - 1) / FROWS), dim3(256), 0, stream,
                           cat + HIDD, CATD, hbfB, cursor, bucket,
                           fLhi + 9216, fLlo + 9216, bl + HIDD,
                           cat + 2 * HIDD, CATD, hbfA);
        hipLaunchKernelGGL(flayer_k, dim3((NN + FROWS - 1) / FROWS), dim3(256), 0, stream,
                           cat + 2 * HIDD, CATD, hbfA, cursor, bucket,
                           fLhi + 2 * 9216, fLlo + 2 * 9216, bl + 2 * HIDD,
                           cat + 3 * HIDD, CATD, (ushort*)nullptr);
        hipLaunchKernelGGL(fgemm_k, dim3((NN + 31) / 32), dim3(256), 0, stream,
                           cat, fOhi, fOlo, bo, out);
    } else {
        float* hA = big;                           // [NN][96]
        float* hB = hA + (size_t)NN * HIDD;        // [NN][96]
        hipLaunchKernelGGL((mgemm_k<IND, HIDD, 32, false>),
                           dim3((NN + 31) / 32), dim3(256), 0, stream,
                           x, whi_in, wlo_in, IND, bi, hA, HIDD, NN, hbfA);
        hipLaunchKernelGGL((mgemm_k<HIDD, OUTD, 64, false>),
                           dim3((NN + 63) / 64), dim3(256), 0, stream,
                           hA, whi_o, wlo_o, CATD, bo, out, OUTD, NN, (ushort*)nullptr);
        const float* hsrc = hA;  float* hdst = hB;
        ushort* bsrc = hbfA;     ushort* bdst = hbfB;
        for (int l = 0; l < 3; l++) {
            hipLaunchKernelGGL(flayer_k, dim3((NN + FROWS - 1) / FROWS), dim3(256), 0, stream,
                               hsrc, HIDD, bsrc, cursor, bucket,
                               fLhi + (size_t)l * 9216, fLlo + (size_t)l * 9216,
                               bl + (size_t)l * HIDD, hdst, HIDD,
                               (l < 2) ? bdst : (ushort*)nullptr);
            hipLaunchKernelGGL((mgemm_k<HIDD, OUTD, 64, true>),
                               dim3((NN + 63) / 64), dim3(256), 0, stream,
                               hdst, whi_o + (size_t)(l + 1) * HIDD,
                               wlo_o + (size_t)(l + 1) * HIDD, CATD,
                               (const float*)nullptr, out, OUTD, NN, (ushort*)nullptr);
            const float* t = hsrc; hsrc = hdst; hdst = (float*)t;
            ushort* tb = bsrc; bsrc = bdst; bdst = tb;
        }
    }
}